// Round 14
// baseline (576.941 us; speedup 1.0000x reference)
//
#include <hip/hip_runtime.h>
#include <cstddef>

#define NNODES 40000
#define NEDGES 640000
#define NETOT  (NNODES + NEDGES)
#define ELLW   96          // fixed edge slots per node; overflow -> spill list
#define NBUCK  313         // dst>>7 buckets (128 nodes each)
#define SEGCAP 8192        // pairs per bucket segment (expected ~2300, +129 sigma)
#define ABLOCKS 84         // ceil(NETOT / 8192) edge-bucketing blocks
#define CBLOCKS 30         // weight-cast blocks (30720 float4 groups / 1024)
#define ACB (ABLOCKS + CBLOCKS)
#define GBLK   625         // NNODES / 64 row-blocks

typedef unsigned short u16;
typedef unsigned int   u32;
using v2f = __attribute__((ext_vector_type(2))) float;

// ---------------- helpers ----------------
__device__ inline float wave_sum(float v) {
#pragma unroll
    for (int o = 32; o > 0; o >>= 1) v += __shfl_xor(v, o);
    return v;
}
__device__ inline u16 f2bf(float f) {   // round-to-nearest-even f32 -> bf16
    u32 u = __float_as_uint(f);
    return (u16)((u + 0x7fffu + ((u >> 16) & 1u)) >> 16);
}
__device__ inline float bfl(u32 w) { return __uint_as_float(w << 16); }
__device__ inline float bfh(u32 w) { return __uint_as_float(w & 0xffff0000u); }

// ---------------- build phase A: edge bucketing + weight cast + prep_v + prep_v3 + bcomb/cvec ----
__global__ void build_a_kernel(const int* __restrict__ ei, u32* __restrict__ bcnt,
                               u32* __restrict__ seg,
                               const float* __restrict__ W1, const float* __restrict__ as1,
                               const float* __restrict__ ad1, float* __restrict__ vbuf,
                               const float* __restrict__ W3, const float* __restrict__ as3,
                               const float* __restrict__ ad3, float* __restrict__ v3buf,
                               const float* __restrict__ fwf, const float* __restrict__ bg3,
                               const float* __restrict__ fbf,
                               u16* __restrict__ bcomb, float* __restrict__ cvec,
                               const float* s0, u16* d0, int n0, const float* s1, u16* d1, int n1,
                               const float* s2, u16* d2, int n2, const float* s3, u16* d3, int n3,
                               const float* s4, u16* d4, int n4, const float* s5, u16* d5, int n5) {
    int tid = threadIdx.x;
    int blk = blockIdx.x;
    if (blk >= ABLOCKS) {
        if (blk < ACB) {                          // ---- weight cast (float4 groups) ----
            int i = (blk - ABLOCKS) * 1024 + tid;
            const float* s; u16* d;
            if      (i < n0) { s = s0; d = d0; }
            else if ((i -= n0) < n1) { s = s1; d = d1; }
            else if ((i -= n1) < n2) { s = s2; d = d2; }
            else if ((i -= n2) < n3) { s = s3; d = d3; }
            else if ((i -= n3) < n4) { s = s4; d = d4; }
            else if ((i -= n4) < n5) { s = s5; d = d5; }
            else return;
            float4 v = ((const float4*)s)[i];
            ushort4 o; o.x = f2bf(v.x); o.y = f2bf(v.y); o.z = f2bf(v.z); o.w = f2bf(v.w);
            ((ushort4*)d)[i] = o;
        } else if (blk == ACB) {                  // ---- prep_v: v_s[h]=W1_h^T a_s1[h] ----
            if (tid < 256) {
                int h = tid >> 6, k = tid & 63;
                float ss = 0.f, dd = 0.f;
                for (int c = 0; c < 64; c++) {
                    float w = W1[(h * 64 + c) * 64 + k];
                    ss += as1[h * 64 + c] * w;
                    dd += ad1[h * 64 + c] * w;
                }
                vbuf[tid] = ss;
                vbuf[256 + tid] = dd;
            }
        } else if (blk == ACB + 1) {              // ---- prep_v3: v3 = W3^T a_s3 ----
            if (tid < 128) {
                float ss = 0.f, dd = 0.f;
                for (int c = 0; c < 128; c++) {
                    float w = W3[c * 128 + tid];
                    ss += as3[c] * w;
                    dd += ad3[c] * w;
                }
                v3buf[tid] = ss;
                v3buf[128 + tid] = dd;
            }
        } else if (blk < ACB + 2 + 32) {          // ---- bcomb: [fw1@W3 | fw2] bf16 ----
            int e = (blk - (ACB + 2)) * 1024 + tid;   // 0..32767
            int o = e >> 8, d = e & 255;
            if (d < 128) {
                float s = 0.f;
                for (int k = 0; k < 128; k++) s += fwf[o * 256 + k] * W3[k * 128 + d];
                bcomb[o * 256 + d] = f2bf(s);
            } else {
                bcomb[o * 256 + d] = f2bf(fwf[o * 256 + d]);
            }
        } else {                                  // ---- cvec = fw1@bg3 + fb ----
            if (tid < 128) {
                float s = fbf[tid];
                for (int k = 0; k < 128; k++) s += fwf[tid * 256 + k] * bg3[k];
                cvec[tid] = s;
            }
        }
        return;
    }
    __shared__ u32 hist[NBUCK], hbase[NBUCK];
    for (int i = tid; i < NBUCK; i += 1024) hist[i] = 0;
    __syncthreads();
    u32 pk[8], loc[8]; int bj[8];
    int g0 = blk * 8192;
#pragma unroll
    for (int j = 0; j < 8; j++) {
        int g = g0 + j * 1024 + tid;
        bj[j] = -1;
        if (g < NETOT) {
            int src, dst;
            if (g < NEDGES) { src = ei[g]; dst = ei[NEDGES + g]; }
            else            { src = g - NEDGES; dst = src; }
            int b = dst >> 7;
            pk[j] = ((u32)dst << 16) | (u32)src;
            bj[j] = b;
            loc[j] = atomicAdd(&hist[b], 1u);
        }
    }
    __syncthreads();
    for (int i = tid; i < NBUCK; i += 1024) {
        u32 c = hist[i];
        hbase[i] = c ? atomicAdd(&bcnt[i], c) : 0u;
    }
    __syncthreads();
#pragma unroll
    for (int j = 0; j < 8; j++) {
        if (bj[j] >= 0) {
            u32 pos = hbase[bj[j]] + loc[j];
            if (pos < SEGCAP) seg[(size_t)bj[j] * SEGCAP + pos] = pk[j];
        }
    }
}

// ---------------- mid kernel: build_b (ELL fill) + esed1 (layer-1 scores/cast) + pn12 ----------------
__global__ void mid_kernel(const u32* __restrict__ seg, const u32* __restrict__ bcnt,
                           int* __restrict__ cnt, u16* __restrict__ srcs16,
                           int2* __restrict__ ovbuf,
                           const float* __restrict__ x, const float* __restrict__ vbuf,
                           float* __restrict__ es, float* __restrict__ ed, u16* __restrict__ xc,
                           const float* __restrict__ pos,
                           const float* __restrict__ pw1, const float* __restrict__ pb1,
                           const float* __restrict__ bn1g, const float* __restrict__ bn1b,
                           const u16* __restrict__ Bpn, u16* __restrict__ p2out,
                           const float* __restrict__ pb2,
                           const float* __restrict__ bn2g, const float* __restrict__ bn2b) {
    __shared__ u32 lcnt[128];
    __shared__ float vl[512];
    int tid = threadIdx.x;
    int blk = blockIdx.x;

    if (blk < NBUCK) {                            // ---- build_b: per-bucket ELL fill ----
        int base = blk << 7;
        if (tid < 128) lcnt[tid] = 0;
        __syncthreads();
        u32 m = bcnt[blk]; if (m > SEGCAP) m = SEGCAP;
        const u32* sp = seg + (size_t)blk * SEGCAP;
        for (u32 e = tid; e < m; e += 256) {
            u32 pkv = sp[e];
            u32 dst = pkv >> 16, src = pkv & 0xffffu;
            u32 p = atomicAdd(&lcnt[dst - (u32)base], 1u);
            if (p < ELLW) srcs16[dst * ELLW + p] = (u16)src;
            else {
                int q = atomicAdd(&cnt[NNODES], 1);   // rare spill
                ovbuf[q] = make_int2((int)dst, (int)src);
            }
        }
        __syncthreads();
        if (tid < 128 && base + tid < NNODES) cnt[base + tid] = (int)lcnt[tid];
        return;
    }
    blk -= NBUCK;
    if (blk < GBLK) {                             // ---- esed1: es/ed = x.v + cast x->bf16 ----
        vl[tid] = vbuf[tid];
        vl[tid + 256] = vbuf[tid + 256];
        __syncthreads();
        int lane = tid & 63, wave = tid >> 6;
        int i = lane >> 2, q = lane & 3;
        int node = blk * 64 + wave * 16 + i;
        const float* xp = x + (size_t)node * 64 + q * 16;
        float xr[16];
        *(float4*)&xr[0]  = ((const float4*)xp)[0];
        *(float4*)&xr[4]  = ((const float4*)xp)[1];
        *(float4*)&xr[8]  = ((const float4*)xp)[2];
        *(float4*)&xr[12] = ((const float4*)xp)[3];
        float p[8];
#pragma unroll
        for (int h = 0; h < 8; h++) {
            float s = 0.f;
#pragma unroll
            for (int j = 0; j < 16; j++) s += xr[j] * vl[h * 64 + q * 16 + j];
            p[h] = s;
        }
#pragma unroll
        for (int h = 0; h < 8; h++) {
            p[h] += __shfl_xor(p[h], 1);
            p[h] += __shfl_xor(p[h], 2);
        }
        es[node * 4 + q] = p[q];
        ed[node * 4 + q] = p[4 + q];
        u16* cp = xc + (size_t)node * 64 + q * 16;
#pragma unroll
        for (int j = 0; j < 16; j += 4) {
            ushort4 o; o.x = f2bf(xr[j]); o.y = f2bf(xr[j + 1]);
            o.z = f2bf(xr[j + 2]); o.w = f2bf(xr[j + 3]);
            *(ushort4*)(cp + j) = o;
        }
        return;
    }
    blk -= GBLK;                                  // ---- pn12 ----
    {
        const int Nn = 128, K = 64;
        using bfrag = __attribute__((ext_vector_type(8))) short;
        using ffrag = __attribute__((ext_vector_type(4))) float;
        int wave = tid >> 6, lane = tid & 63;
        int lm = lane & 15, kg = (lane >> 4) * 8;
        int rowblk = blk * 64 + wave * 16;
        int row = rowblk + lm;
        float p0 = pos[row * 3 + 0], p1 = pos[row * 3 + 1], p2 = pos[row * 3 + 2];
        const u16* Bp = Bpn + (size_t)lm * K + kg;
        const float bnscale = rsqrtf(1.0f + 1e-5f);
        ffrag acc[8] = {};
#pragma unroll
        for (int k0 = 0; k0 < K; k0 += 32) {
            bfrag af;
#pragma unroll
            for (int j = 0; j < 8; j++) {
                int k = kg + k0 + j;
                float v = p0 * pw1[k * 3 + 0] + p1 * pw1[k * 3 + 1] + p2 * pw1[k * 3 + 2] + pb1[k];
                v = v * (bn1g[k] * bnscale) + bn1b[k];
                v = v > 0.f ? v : 0.f;
                af[j] = (short)f2bf(v);
            }
#pragma unroll
            for (int t = 0; t < 8; t++) {
                bfrag bf = *(const bfrag*)(Bp + (size_t)t * 16 * K + k0);
                acc[t] = __builtin_amdgcn_mfma_f32_16x16x32_bf16(af, bf, acc[t], 0, 0, 0);
            }
        }
        int orow = rowblk + (lane >> 4) * 4;
#pragma unroll
        for (int t = 0; t < 8; t++) {
            int col = t * 16 + lm;
            float bi = pb2[col], g = bn2g[col] * bnscale, bb = bn2b[col];
#pragma unroll
            for (int r = 0; r < 4; r++) {
                float v = (acc[t][r] + bi) * g + bb;
                v = v > 0.f ? v : 0.f;
                p2out[(size_t)(orow + r) * Nn + col] = f2bf(v);
            }
        }
    }
}

// ---------------- layer-1 fused: gather-aggregate x + per-node W1 transform + LN + ReLU -> xb ----
// Epilogue is per-node-local: wave broadcasts its f32 aggregate via LDS, reads W1 rows from
// L1/L2 (w1c = 32KB, cache-resident), 256 FMAs/lane, LN, writes xb. No aggb round-trip.
__global__ void gat1_kernel(const u16* __restrict__ xc,
                            const float* __restrict__ es, const float* __restrict__ ed,
                            const int* __restrict__ cnt, const u16* __restrict__ srcs16,
                            const int2* __restrict__ ovbuf,
                            const u16* __restrict__ w1c, const float* __restrict__ bg1,
                            const float* __restrict__ ln1g, const float* __restrict__ ln1b,
                            u16* __restrict__ xb, int n) {
    __shared__ float wbuf[4][4][100];
    __shared__ u32   sbuf[4][ELLW];
    __shared__ float aggl[4][256];
    int wave = threadIdx.x >> 6;
    int wid = (blockIdx.x * blockDim.x + threadIdx.x) >> 6;
    int lane = threadIdx.x & 63;
    if (wid >= n) return;

    int degt = cnt[wid];
    int mainc = degt < ELLW ? degt : ELLW;
    int padt = (mainc + 7) & ~7;
    const u16* sp = srcs16 + (size_t)wid * ELLW;

    const int h = lane & 3;
    const int esub = lane >> 2;
    float edh = ed[(size_t)wid * 4 + h];

    // ---- phase 1 ----
    float den = 0.f;
    for (int i0 = 0; i0 < padt; i0 += 16) {
        int e = i0 + esub;
        if (e < padt) {
            float w = 0.f; u32 off = 0;
            if (e < mainc) {
                int s = sp[e];
                off = (u32)s << 7;
                float v = es[(size_t)s * 4 + h] + edh;
                v = v > 0.f ? v : 0.2f * v;
                w = __expf(v);
            }
            wbuf[wave][h][e] = w;
            if (h == 0) sbuf[wave][e] = off;
            den += w;
        }
    }
    int ovn = 0;
    if (degt > ELLW) {
        ovn = cnt[n];
        for (int j = esub; j < ovn; j += 16) {
            int2 t = ovbuf[j];
            if (t.x == wid) {
                float v = es[(size_t)t.y * 4 + h] + edh;
                v = v > 0.f ? v : 0.2f * v;
                den += __expf(v);
            }
        }
    }
#pragma unroll
    for (int o = 4; o < 64; o <<= 1) den += __shfl_xor(den, o);
    float inv = 1.f / (den + 1e-16f);

    // ---- phase 2: gather 128B rows, accumulate all 4 heads ----
    const int e2 = lane >> 5, f16 = lane & 31;
    const char* hp = (const char*)xc + f16 * 4;
    v2f a0 = {0.f, 0.f}, a1 = {0.f, 0.f}, a2 = {0.f, 0.f}, a3 = {0.f, 0.f};
    for (int eb = 0; eb < padt; eb += 8) {
        u32 of[4]; u32 g[4];
        float w0[4], w1[4], w2[4], w3[4];
#pragma unroll
        for (int k = 0; k < 4; k++) of[k] = sbuf[wave][eb + 2 * k + e2];
#pragma unroll
        for (int k = 0; k < 4; k++) g[k] = *(const u32*)(hp + of[k]);
#pragma unroll
        for (int k = 0; k < 4; k++) {
            int e = eb + 2 * k + e2;
            w0[k] = wbuf[wave][0][e]; w1[k] = wbuf[wave][1][e];
            w2[k] = wbuf[wave][2][e]; w3[k] = wbuf[wave][3][e];
        }
#pragma unroll
        for (int k = 0; k < 4; k++) {
            v2f hx; hx.x = bfl(g[k]); hx.y = bfh(g[k]);
            a0 += v2f{w0[k], w0[k]} * hx;
            a1 += v2f{w1[k], w1[k]} * hx;
            a2 += v2f{w2[k], w2[k]} * hx;
            a3 += v2f{w3[k], w3[k]} * hx;
        }
    }
    if (degt > ELLW) {
        for (int j = 0; j < ovn; j++) {
            int2 t = ovbuf[j];
            if (t.x != wid) continue;
            float wh[4];
#pragma unroll
            for (int hh = 0; hh < 4; hh++) {
                float v = es[(size_t)t.y * 4 + hh] + __shfl(edh, hh);
                v = v > 0.f ? v : 0.2f * v;
                wh[hh] = __expf(v);
            }
            if (lane < 32) {
                u32 g = *(const u32*)(hp + ((u32)t.y << 7));
                v2f hx; hx.x = bfl(g); hx.y = bfh(g);
                a0 += v2f{wh[0], wh[0]} * hx;
                a1 += v2f{wh[1], wh[1]} * hx;
                a2 += v2f{wh[2], wh[2]} * hx;
                a3 += v2f{wh[3], wh[3]} * hx;
            }
        }
    }
    a0.x += __shfl_xor(a0.x, 32); a0.y += __shfl_xor(a0.y, 32);
    a1.x += __shfl_xor(a1.x, 32); a1.y += __shfl_xor(a1.y, 32);
    a2.x += __shfl_xor(a2.x, 32); a2.y += __shfl_xor(a2.y, 32);
    a3.x += __shfl_xor(a3.x, 32); a3.y += __shfl_xor(a3.y, 32);
    float iv[4];
#pragma unroll
    for (int hh = 0; hh < 4; hh++) iv[hh] = __shfl(inv, hh);
    if (lane < 32) {   // broadcast f32 aggregate (wave-synchronous LDS, no barrier needed)
        aggl[wave][0 * 64 + 2 * f16]     = a0.x * iv[0];
        aggl[wave][0 * 64 + 2 * f16 + 1] = a0.y * iv[0];
        aggl[wave][1 * 64 + 2 * f16]     = a1.x * iv[1];
        aggl[wave][1 * 64 + 2 * f16 + 1] = a1.y * iv[1];
        aggl[wave][2 * 64 + 2 * f16]     = a2.x * iv[2];
        aggl[wave][2 * 64 + 2 * f16 + 1] = a2.y * iv[2];
        aggl[wave][3 * 64 + 2 * f16]     = a3.x * iv[3];
        aggl[wave][3 * 64 + 2 * f16 + 1] = a3.y * iv[3];
    }

    // ---- epilogue: y[4] = agg_h @ W1_h^T rows [4*lane..4*lane+4) + bias; LN; ReLU; write ----
    const int ho = lane >> 4;                    // head of this lane's 4 outputs
    const float* av = &aggl[wave][ho * 64];
    float y[4];
#pragma unroll
    for (int i = 0; i < 4; i++) {
        int orow = lane * 4 + i;
        const u16* wr = w1c + (size_t)orow * 64;
        float s = 0.f;
#pragma unroll
        for (int kc = 0; kc < 64; kc += 8) {
            float4 av0 = *(const float4*)&av[kc];
            float4 av1 = *(const float4*)&av[kc + 4];
            uint4 wv = *(const uint4*)(wr + kc);
            s += av0.x * bfl(wv.x) + av0.y * bfh(wv.x);
            s += av0.z * bfl(wv.y) + av0.w * bfh(wv.y);
            s += av1.x * bfl(wv.z) + av1.y * bfh(wv.z);
            s += av1.z * bfl(wv.w) + av1.w * bfh(wv.w);
        }
        y[i] = s + bg1[orow];
    }
    float s1 = 0.f, s2 = 0.f;
#pragma unroll
    for (int i = 0; i < 4; i++) { s1 += y[i]; s2 += y[i] * y[i]; }
    s1 = wave_sum(s1);
    s2 = wave_sum(s2);
    float mu = s1 / 256.f;
    float var = s2 / 256.f - mu * mu;
    float rstd = rsqrtf(var + 1e-5f);
    int fbase = lane * 4;
    ushort4 o;
    {
        float v0 = (y[0] - mu) * rstd * ln1g[fbase + 0] + ln1b[fbase + 0];
        float v1 = (y[1] - mu) * rstd * ln1g[fbase + 1] + ln1b[fbase + 1];
        float v2 = (y[2] - mu) * rstd * ln1g[fbase + 2] + ln1b[fbase + 2];
        float v3 = (y[3] - mu) * rstd * ln1g[fbase + 3] + ln1b[fbase + 3];
        o.x = f2bf(v0 > 0.f ? v0 : 0.f);
        o.y = f2bf(v1 > 0.f ? v1 : 0.f);
        o.z = f2bf(v2 > 0.f ? v2 : 0.f);
        o.w = f2bf(v3 > 0.f ? v3 : 0.f);
    }
    *(ushort4*)&xb[(size_t)wid * 256 + fbase] = o;
}

// ---------------- merged: gs2 (layer-2 GEMM + scores, K=256) || pf = p2@pw3^T + pb3 ----------------
__global__ __launch_bounds__(256, 2) void gs2pf_kernel(
        const u16* __restrict__ xb, const u16* __restrict__ B2, u16* __restrict__ Cout,
        const float* __restrict__ as2, const float* __restrict__ ad2,
        float* __restrict__ es, float* __restrict__ ed,
        const u16* __restrict__ p2, const u16* __restrict__ Bpw3,
        const float* __restrict__ pb3, float* __restrict__ pf, u16* __restrict__ pfb, int M) {
    using bfrag = __attribute__((ext_vector_type(8))) short;
    using ffrag = __attribute__((ext_vector_type(4))) float;
    __shared__ u16 bl[128][136];
    int tid = threadIdx.x;
    int blk = blockIdx.x;
    int wave = tid >> 6, lane = tid & 63;
    int lm = lane & 15, kg = (lane >> 4) * 8;
    if (blk < GBLK) {
        // ---- gs2: h2 = xb@W2^T, H=2, C=64, K=256, plus attention scores ----
        int rowblk = blk * 64 + wave * 16;
        const u16* Bp = B2 + (size_t)lm * 256 + kg;
        ffrag acc[8] = {};
        for (int k0 = 0; k0 < 256; k0 += 32) {
            bfrag af = *(const bfrag*)(xb + (size_t)(rowblk + lm) * 256 + kg + k0);
            bfrag bfs[8];
#pragma unroll
            for (int t = 0; t < 8; t++)
                bfs[t] = *(const bfrag*)(Bp + (size_t)t * 16 * 256 + k0);
#pragma unroll
            for (int t = 0; t < 8; t++)
                acc[t] = __builtin_amdgcn_mfma_f32_16x16x32_bf16(af, bfs[t], acc[t], 0, 0, 0);
        }
        int orow = rowblk + (lane >> 4) * 4;
        float asv[8], adv[8];
#pragma unroll
        for (int t = 0; t < 8; t++) {
            int fcol = t * 16 + lm;
            asv[t] = as2[fcol]; adv[t] = ad2[fcol];
        }
        float ps[4][2] = {}, pd[4][2] = {};
#pragma unroll
        for (int t = 0; t < 8; t++) {
            const int hh = t >> 2;
#pragma unroll
            for (int r = 0; r < 4; r++) {
                float v = acc[t][r];
                ps[r][hh] += v * asv[t];
                pd[r][hh] += v * adv[t];
                Cout[(size_t)(orow + r) * 128 + t * 16 + lm] = f2bf(v);
            }
        }
#pragma unroll
        for (int r = 0; r < 4; r++)
#pragma unroll
            for (int hh = 0; hh < 2; hh++) {
                float s = ps[r][hh], d = pd[r][hh];
#pragma unroll
                for (int o = 1; o < 16; o <<= 1) { s += __shfl_xor(s, o); d += __shfl_xor(d, o); }
                if (lm == 0) {
                    es[(size_t)(orow + r) * 2 + hh] = s;
                    ed[(size_t)(orow + r) * 2 + hh] = d;
                }
            }
    } else {
        blk -= GBLK;
        // ---- pf = p2@pw3^T + pb3 (K=128), LDS-staged B; writes pf (f32) + pfb (bf16) ----
        for (int i = tid; i < 2048; i += 256) {
            int r = i >> 4, c = (i & 15) * 8;
            *(uint4*)&bl[r][c] = *(const uint4*)(Bpw3 + (size_t)r * 128 + c);
        }
        __syncthreads();
        int row = blk * 64 + wave * 16 + lm;
        bfrag afs[4];
#pragma unroll
        for (int i = 0; i < 4; i++)
            afs[i] = *(const bfrag*)(p2 + (size_t)row * 128 + kg + i * 32);
        ffrag acc[8] = {};
#pragma unroll
        for (int k = 0; k < 4; k++)
#pragma unroll
            for (int t = 0; t < 8; t++) {
                bfrag bf = *(const bfrag*)&bl[t * 16 + lm][kg + k * 32];
                acc[t] = __builtin_amdgcn_mfma_f32_16x16x32_bf16(afs[k], bf, acc[t], 0, 0, 0);
            }
        int orow = blk * 64 + wave * 16 + (lane >> 4) * 4;
#pragma unroll
        for (int t = 0; t < 8; t++) {
            int col = t * 16 + lm;
            float bi = pb3[col];
#pragma unroll
            for (int r = 0; r < 4; r++) {
                float v = acc[t][r] + bi;
                pf[(size_t)(orow + r) * 128 + col] = v;
                pfb[(size_t)(orow + r) * 128 + col] = f2bf(v);
            }
        }
    }
}

// ---------------- layer-2 fused GAT (H=2,C=64) + LN + ReLU + layer-3 scores ----------------
__global__ void gat2_kernel(const u16* __restrict__ hmat,
                            const float* __restrict__ es, const float* __restrict__ ed,
                            const int* __restrict__ cnt, const u16* __restrict__ srcs16,
                            const int2* __restrict__ ovbuf,
                            const float* __restrict__ bias,
                            const float* __restrict__ lng, const float* __restrict__ lnb,
                            u16* __restrict__ xb,
                            const float* __restrict__ v3, const float* __restrict__ v3d,
                            float* __restrict__ es3o, float* __restrict__ ed3o, int n) {
    constexpr int H = 2, HC = 128, VPT = 2, SH = 8, EPW = 32, HSH = 1;
    __shared__ float wbuf[4][H][100];
    __shared__ int   sbuf[4][ELLW];
    int wave = threadIdx.x >> 6;
    int wid = (blockIdx.x * blockDim.x + threadIdx.x) >> 6;
    int lane = threadIdx.x & 63;
    if (wid >= n) return;

    int degt = cnt[wid];
    int mainc = degt < ELLW ? degt : ELLW;
    int pad = (mainc + 7) & ~7;
    const u16* sp = srcs16 + (size_t)wid * ELLW;

    const int h = lane & (H - 1);
    const int esub = lane >> HSH;
    float edh = ed[(size_t)wid * H + h];

    // ---- phase 1 ----
    float den = 0.f;
    for (int i0 = 0; i0 < pad; i0 += EPW) {
        int e = i0 + esub;
        if (e < pad) {
            float w = 0.f;
            int soff = 0;
            if (e < mainc) {
                int s = sp[e];
                soff = s << SH;
                float v = es[(size_t)s * H + h] + edh;
                v = v > 0.f ? v : 0.2f * v;
                w = __expf(v);
            }
            wbuf[wave][h][e] = w;
            if (h == 0) sbuf[wave][e] = soff;
            den += w;
        }
    }
    int ovn = 0;
    if (degt > ELLW) {
        ovn = cnt[n];
        for (int j = esub; j < ovn; j += EPW) {
            int2 t = ovbuf[j];
            if (t.x == wid) {
                float v = es[(size_t)t.y * H + h] + edh;
                v = v > 0.f ? v : 0.2f * v;
                den += __expf(v);
            }
        }
    }
#pragma unroll
    for (int o = H; o < 64; o <<= 1) den += __shfl_xor(den, o);
    float inv = 1.f / (den + 1e-16f);

    // ---- phase 2: 8-deep batches ----
    const int myhead = (lane * VPT) / 64;
    const float invh = __shfl(inv, myhead);
    const int loff = lane * (VPT * 2);
    v2f a01 = {0.f, 0.f};

    for (int e = 0; e < pad; e += 8) {
        int4   o0 = *(const int4*)&sbuf[wave][e];
        int4   o1 = *(const int4*)&sbuf[wave][e + 4];
        float4 w0 = *(const float4*)&wbuf[wave][myhead][e];
        float4 w1 = *(const float4*)&wbuf[wave][myhead][e + 4];
        int   oo[8] = {o0.x, o0.y, o0.z, o0.w, o1.x, o1.y, o1.z, o1.w};
        float ww[8] = {w0.x, w0.y, w0.z, w0.w, w1.x, w1.y, w1.z, w1.w};
        u32 gg[8];
#pragma unroll
        for (int u = 0; u < 8; u++)
            gg[u] = *(const u32*)((const char*)hmat + (size_t)(u32)oo[u] + loff);
#pragma unroll
        for (int u = 0; u < 8; u++) {
            v2f wv = {ww[u], ww[u]};
            v2f h01; h01.x = bfl(gg[u]); h01.y = bfh(gg[u]);
            a01 += wv * h01;
        }
    }
    if (degt > ELLW) {
        const float edm = __shfl(edh, myhead);
        for (int j = 0; j < ovn; j++) {
            int2 t = ovbuf[j];
            if (t.x != wid) continue;
            float v = es[(size_t)t.y * H + myhead] + edm;
            v = v > 0.f ? v : 0.2f * v;
            float w = __expf(v);
            u32 g = *(const u32*)((const char*)hmat + ((size_t)t.y << SH) + loff);
            v2f h01; h01.x = bfl(g); h01.y = bfh(g);
            a01 += v2f{w, w} * h01;
        }
    }
    a01 *= v2f{invh, invh};

    int fbase = lane * VPT;
    float y[2];
    y[0] = a01.x + bias[fbase + 0];
    y[1] = a01.y + bias[fbase + 1];

    float s1 = y[0] + y[1], s2 = y[0] * y[0] + y[1] * y[1];
    s1 = wave_sum(s1);
    s2 = wave_sum(s2);
    float mu = s1 / (float)HC;
    float var = s2 / (float)HC - mu * mu;
    float rstd = rsqrtf(var + 1e-5f);
#pragma unroll
    for (int j = 0; j < 2; j++) {
        float v = (y[j] - mu) * rstd * lng[fbase + j] + lnb[fbase + j];
        y[j] = v > 0.f ? v : 0.f;
    }
    // layer-3 scores from this node's xb row (prep_v trick)
    float s3 = y[0] * v3[fbase] + y[1] * v3[fbase + 1];
    float d3 = y[0] * v3d[fbase] + y[1] * v3d[fbase + 1];
    s3 = wave_sum(s3);
    d3 = wave_sum(d3);
    if (lane == 0) { es3o[wid] = s3; ed3o[wid] = d3; }

    ushort2 o; o.x = f2bf(y[0]); o.y = f2bf(y[1]);
    *(ushort2*)&xb[(size_t)wid * HC + fbase] = o;
}

// ---------------- layer-3 fused: gather-aggregate xb + per-node W3 transform -> x3, agg3b ----
__global__ void gat3_kernel(const u16* __restrict__ hmat,
                            const float* __restrict__ es3, const float* __restrict__ ed3,
                            const int* __restrict__ cnt, const u16* __restrict__ srcs16,
                            const int2* __restrict__ ovbuf,
                            const u16* __restrict__ w3c, const float* __restrict__ bg3,
                            float* __restrict__ x3, u16* __restrict__ agg3b, int n) {
    __shared__ float wbuf1[4][100];
    __shared__ u32   sbuf[4][ELLW];
    __shared__ float aggl[4][128];
    int wave = threadIdx.x >> 6;
    int wid = (blockIdx.x * blockDim.x + threadIdx.x) >> 6;
    int lane = threadIdx.x & 63;
    if (wid >= n) return;

    int degt = cnt[wid];
    int mainc = degt < ELLW ? degt : ELLW;
    int pad = (mainc + 7) & ~7;
    const u16* sp = srcs16 + (size_t)wid * ELLW;
    float edh = ed3[wid];

    // ---- phase 1 (H=1) ----
    float den = 0.f;
    for (int e = lane; e < pad; e += 64) {
        float w = 0.f;
        int soff = 0;
        if (e < mainc) {
            int s = sp[e];
            soff = s << 8;                       // rows of 128 bf16 = 256B
            float v = es3[s] + edh;
            v = v > 0.f ? v : 0.2f * v;
            w = __expf(v);
        }
        wbuf1[wave][e] = w;
        sbuf[wave][e] = soff;
        den += w;
    }
    int ovn = 0;
    if (degt > ELLW) {
        ovn = cnt[n];
        for (int j = lane; j < ovn; j += 64) {
            int2 t = ovbuf[j];
            if (t.x == wid) {
                float v = es3[t.y] + edh;
                v = v > 0.f ? v : 0.2f * v;
                den += __expf(v);
            }
        }
    }
    den = wave_sum(den);
    float inv = 1.f / (den + 1e-16f);

    // ---- phase 2: 8-deep batches, each lane owns features [2*lane, 2*lane+1] ----
    const int loff = lane * 4;
    v2f a01 = {0.f, 0.f};
    for (int e = 0; e < pad; e += 8) {
        int4   o0 = *(const int4*)&sbuf[wave][e];
        int4   o1 = *(const int4*)&sbuf[wave][e + 4];
        float4 w0 = *(const float4*)&wbuf1[wave][e];
        float4 w1 = *(const float4*)&wbuf1[wave][e + 4];
        int   oo[8] = {o0.x, o0.y, o0.z, o0.w, o1.x, o1.y, o1.z, o1.w};
        float ww[8] = {w0.x, w0.y, w0.z, w0.w, w1.x, w1.y, w1.z, w1.w};
        u32 gg[8];
#pragma unroll
        for (int u = 0; u < 8; u++)
            gg[u] = *(const u32*)((const char*)hmat + (size_t)(u32)oo[u] + loff);
#pragma unroll
        for (int u = 0; u < 8; u++) {
            v2f wv = {ww[u], ww[u]};
            v2f h01; h01.x = bfl(gg[u]); h01.y = bfh(gg[u]);
            a01 += wv * h01;
        }
    }
    if (degt > ELLW) {
        for (int j = 0; j < ovn; j++) {
            int2 t = ovbuf[j];
            if (t.x != wid) continue;
            float v = es3[t.y] + edh;
            v = v > 0.f ? v : 0.2f * v;
            float w = __expf(v);
            u32 g = *(const u32*)((const char*)hmat + ((size_t)t.y << 8) + loff);
            v2f h01; h01.x = bfl(g); h01.y = bfh(g);
            a01 += v2f{w, w} * h01;
        }
    }
    a01 *= v2f{inv, inv};

    // broadcast f32 aggregate (wave-synchronous) + bf16 shadow for out_kernel
    int fbase = lane * 2;
    aggl[wave][fbase]     = a01.x;
    aggl[wave][fbase + 1] = a01.y;
    {
        ushort2 o; o.x = f2bf(a01.x); o.y = f2bf(a01.y);
        *(ushort2*)&agg3b[(size_t)wid * 128 + fbase] = o;
    }

    // ---- epilogue: x3 rows [2*lane, 2*lane+1] = agg3 @ W3^T + bg3 ----
    const float* av = aggl[wave];
    const u16* w0r = w3c + (size_t)fbase * 128;
    const u16* w1r = w0r + 128;
    float y0 = bg3[fbase], y1 = bg3[fbase + 1];
#pragma unroll
    for (int kc = 0; kc < 128; kc += 8) {
        float4 av0 = *(const float4*)&av[kc];
        float4 av1 = *(const float4*)&av[kc + 4];
        uint4 wa = *(const uint4*)(w0r + kc);
        uint4 wb = *(const uint4*)(w1r + kc);
        y0 += av0.x * bfl(wa.x) + av0.y * bfh(wa.x);
        y0 += av0.z * bfl(wa.y) + av0.w * bfh(wa.y);
        y0 += av1.x * bfl(wa.z) + av1.y * bfh(wa.z);
        y0 += av1.z * bfl(wa.w) + av1.w * bfh(wa.w);
        y1 += av0.x * bfl(wb.x) + av0.y * bfh(wb.x);
        y1 += av0.z * bfl(wb.y) + av0.w * bfh(wb.y);
        y1 += av1.x * bfl(wb.z) + av1.y * bfh(wb.z);
        y1 += av1.z * bfl(wb.w) + av1.w * bfh(wb.w);
    }
    *(float2*)&x3[(size_t)wid * 128 + fbase] = make_float2(y0, y1);
}

// ---------------- out = [agg3|pfb]@bcomb^T + cvec (K=256), LDS-staged B ----------------
__global__ void out_kernel(const u16* __restrict__ agg3b, const u16* __restrict__ pfb,
                           const u16* __restrict__ bcomb, const float* __restrict__ cvec,
                           float* __restrict__ outp, int M) {
    using bfrag = __attribute__((ext_vector_type(8))) short;
    using ffrag = __attribute__((ext_vector_type(4))) float;
    __shared__ u16 bl[128][264];
    int tid = threadIdx.x;
    int blk = blockIdx.x;
    int wave = tid >> 6, lane = tid & 63;
    int lm = lane & 15, kg = (lane >> 4) * 8;
    for (int i = tid; i < 4096; i += 256) {
        int r = i >> 5, c = (i & 31) * 8;
        *(uint4*)&bl[r][c] = *(const uint4*)(bcomb + (size_t)r * 256 + c);
    }
    __syncthreads();
    int row = blk * 64 + wave * 16 + lm;
    bfrag afs[8];
#pragma unroll
    for (int i = 0; i < 4; i++)
        afs[i] = *(const bfrag*)(agg3b + (size_t)row * 128 + kg + i * 32);
#pragma unroll
    for (int i = 0; i < 4; i++)
        afs[4 + i] = *(const bfrag*)(pfb + (size_t)row * 128 + kg + i * 32);
    ffrag acc[8] = {};
#pragma unroll
    for (int k = 0; k < 8; k++)
#pragma unroll
        for (int t = 0; t < 8; t++) {
            bfrag bf = *(const bfrag*)&bl[t * 16 + lm][kg + k * 32];
            acc[t] = __builtin_amdgcn_mfma_f32_16x16x32_bf16(afs[k], bf, acc[t], 0, 0, 0);
        }
    int orow = blk * 64 + wave * 16 + (lane >> 4) * 4;
#pragma unroll
    for (int t = 0; t < 8; t++) {
        int col = t * 16 + lm;
        float bi = cvec[col];
#pragma unroll
        for (int r = 0; r < 4; r++)
            outp[(size_t)(orow + r) * 128 + col] = acc[t][r] + bi;
    }
}

extern "C" void kernel_launch(void* const* d_in, const int* in_sizes, int n_in,
                              void* d_out, int out_size, void* d_ws, size_t ws_size,
                              hipStream_t stream) {
    const float* x    = (const float*)d_in[0];
    const int*   ei   = (const int*)d_in[1];
    const float* pos  = (const float*)d_in[2];
    const float* W1   = (const float*)d_in[3];
    const float* as1  = (const float*)d_in[4];
    const float* ad1  = (const float*)d_in[5];
    const float* bg1  = (const float*)d_in[6];
    const float* ln1g = (const float*)d_in[7];
    const float* ln1b = (const float*)d_in[8];
    const float* W2   = (const float*)d_in[9];
    const float* as2  = (const float*)d_in[10];
    const float* ad2  = (const float*)d_in[11];
    const float* bg2  = (const float*)d_in[12];
    const float* ln2g = (const float*)d_in[13];
    const float* ln2b = (const float*)d_in[14];
    const float* W3   = (const float*)d_in[15];
    const float* as3  = (const float*)d_in[16];
    const float* ad3  = (const float*)d_in[17];
    const float* bg3  = (const float*)d_in[18];
    const float* pw1  = (const float*)d_in[19];
    const float* pb1  = (const float*)d_in[20];
    const float* bn1g = (const float*)d_in[21];
    const float* bn1b = (const float*)d_in[22];
    const float* pw2  = (const float*)d_in[23];
    const float* pb2  = (const float*)d_in[24];
    const float* bn2g = (const float*)d_in[25];
    const float* bn2b = (const float*)d_in[26];
    const float* pw3  = (const float*)d_in[27];
    const float* pb3  = (const float*)d_in[28];
    const float* fw   = (const float*)d_in[29];
    const float* fb   = (const float*)d_in[30];

    const int N = NNODES;
    float* out = (float*)d_out;                    // [N,128]
    float* x3  = out + (size_t)N * 128;            // [N,128]
    float* pf  = out + (size_t)2 * N * 128;        // [N,128]

    char* ws = (char*)d_ws;
    size_t off = 0;
    auto alloc = [&](size_t bytes) -> void* {
        void* p = ws + off;
        off += (bytes + 255) / 256 * 256;
        return p;
    };
    int*   cnt    = (int*)alloc((size_t)(N + 1 + NBUCK) * 4);  // degrees + spill count + bucket cursors
    u32*   bcnt   = (u32*)(cnt + N + 1);
    u32*   seg    = (u32*)alloc((size_t)NBUCK * SEGCAP * 4);   // bucketed packed (dst<<16|src)
    u16*   srcs16 = (u16*)alloc((size_t)N * ELLW * 2);
    int2*  ovbuf  = (int2*)alloc((size_t)NETOT * 8);
    float* esb    = (float*)alloc((size_t)N * 4 * 4);
    float* edb    = (float*)alloc((size_t)N * 4 * 4);
    float* es3b   = (float*)alloc((size_t)N * 4);
    float* ed3b   = (float*)alloc((size_t)N * 4);
    u16*   w1c    = (u16*)alloc(16384 * 2);
    u16*   w2c    = (u16*)alloc(32768 * 2);
    u16*   w3c    = (u16*)alloc(16384 * 2);
    u16*   pw2c   = (u16*)alloc(8192 * 2);
    u16*   pw3c   = (u16*)alloc(16384 * 2);
    u16*   fwc    = (u16*)alloc(32768 * 2);
    u16*   bcomb  = (u16*)alloc(32768 * 2);             // [fw1@W3 | fw2] bf16
    float* cvec   = (float*)alloc(128 * 4);             // fw1@bg3 + fb
    u16*   hbufb  = (u16*)alloc((size_t)N * 128 * 2);   // layer-2 h table
    u16*   xb     = (u16*)alloc((size_t)N * 256 * 2);
    u16*   p2b    = (u16*)alloc((size_t)N * 128 * 2);
    u16*   xc     = (u16*)alloc((size_t)N * 64 * 2);    // layer-1 bf16 x table
    float* vbuf   = (float*)alloc(512 * 4);             // layer-1 v_s/v_d [8][64]
    float* v3buf  = (float*)alloc(256 * 4);             // layer-3 v3/v3d
    u16*   agg3b  = (u16*)alloc((size_t)N * 128 * 2);   // layer-3 aggregate (bf16)
    u16*   pfb    = (u16*)alloc((size_t)N * 128 * 2);   // bf16 shadow of pf

    // ---- graph build phase A + weight cast + prep_v/prep_v3 + bcomb/cvec ----
    hipMemsetAsync(cnt, 0, (size_t)(N + 1 + NBUCK) * 4, stream);
    build_a_kernel<<<ACB + 35, 1024, 0, stream>>>(
        ei, bcnt, seg, W1, as1, ad1, vbuf, W3, as3, ad3, v3buf,
        fw, bg3, fb, bcomb, cvec,
        W1, w1c, 4096, W2, w2c, 8192, W3, w3c, 4096,
        pw2, pw2c, 2048, pw3, pw3c, 4096, fw, fwc, 8192);

    // ---- mid: build_b + esed1 + pn12 (independent, one launch) ----
    mid_kernel<<<NBUCK + 2 * GBLK, 256, 0, stream>>>(
        seg, bcnt, cnt, srcs16, ovbuf,
        x, vbuf, esb, edb, xc,
        pos, pw1, pb1, bn1g, bn1b, pw2c, p2b, pb2, bn2g, bn2b);

    const int NW = N / 4;   // one-wave-per-node kernels
    const int GB = GBLK;    // 625 GEMM row-blocks

    // ---- GAT layer 1: gather + fused W1 transform + LN (writes xb directly) ----
    gat1_kernel<<<NW, 256, 0, stream>>>(
        xc, esb, edb, cnt, srcs16, ovbuf, w1c, bg1, ln1g, ln1b, xb, N);

    // ---- layer-2 GEMM+scores || pf GEMM (independent, merged) ----
    gs2pf_kernel<<<2 * GB, 256, 0, stream>>>(
        xb, w2c, hbufb, as2, ad2, esb, edb,
        p2b, pw3c, pb3, pf, pfb, N);

    // ---- GAT layer 2 (+ fused layer-3 scores) ----
    gat2_kernel<<<NW, 256, 0, stream>>>(
        hbufb, esb, edb, cnt, srcs16, ovbuf, bg2, ln2g, ln2b, xb,
        v3buf, v3buf + 128, es3b, ed3b, N);

    // ---- GAT layer 3: gather xb + fused W3 transform (writes x3 + agg3b) ----
    gat3_kernel<<<NW, 256, 0, stream>>>(
        xb, es3b, ed3b, cnt, srcs16, ovbuf, w3c, bg3, x3, agg3b, N);

    // ---- out = [agg3|pf]@bcomb^T + cvec ----
    out_kernel<<<GB, 256, 0, stream>>>(agg3b, pfb, bcomb, cvec, out, N);
}